// Round 13
// baseline (1072.486 us; speedup 1.0000x reference)
//
#include <hip/hip_runtime.h>
#include <hip/hip_bf16.h>
#include <stdint.h>

#define N_TOK 16384
#define DMODEL 1024
#define EXP 16
#define CAP 4096
#define TT 32768          // N_TOK * K (K=2)

typedef __bf16 bf16x8 __attribute__((ext_vector_type(8)));
typedef __bf16 bf16x4 __attribute__((ext_vector_type(4)));
typedef float  f32x4  __attribute__((ext_vector_type(4)));

__device__ __forceinline__ void gl_lds16(const void* g, void* s) {
  __builtin_amdgcn_global_load_lds(
      (__attribute__((address_space(1))) void*)(void*)g,
      (__attribute__((address_space(3))) void*)s, 16, 0, 0);
}

__device__ __forceinline__ float bfbits2f(unsigned short u) {
  return __uint_as_float(((unsigned)u) << 16);
}

#define FENCE asm volatile("" ::: "memory")
#define BAR() do { FENCE; __builtin_amdgcn_s_barrier(); FENCE; } while (0)

// ------- merged prep, interleaved: bid%9==8 -> gate (1024), else convw (8192) -------
// convw writes W in MFMA-fragment-linear layout:
//   W^T[n][k] -> Wf[e*1M + ((n>>4)*32 + (k>>5))*512 + (((k>>3)&3)*16 + (n&15))*8 + (k&7)]
__global__ __launch_bounds__(256) void prep_kernel(const float* __restrict__ W1,
                                                   const float* __restrict__ W2,
                                                   __bf16* __restrict__ W1bt,
                                                   __bf16* __restrict__ W2bt,
                                                   const float* __restrict__ x,
                                                   const float* __restrict__ gw,
                                                   const float* __restrict__ gb,
                                                   const float* __restrict__ rw,
                                                   const float* __restrict__ rb,
                                                   int* __restrict__ idxo,
                                                   float* __restrict__ sco,
                                                   __bf16* __restrict__ Xb) {
  __shared__ char smem[21504];
  int bid = blockIdx.x;
  int tid = threadIdx.x;
  if (bid % 9 != 8) {
    // ---------------- convw (fragment-linear output) ----------------
    int cb = bid - (bid + 1) / 9;          // 0..8191 bijective
    float (*tile)[65] = (float(*)[65])smem;
    int tx = cb & 15;
    int ty = (cb >> 4) & 15;
    int e  = (cb >> 8) & 15;
    int which = (cb >> 12) & 1;
    const float* src = (which ? W2 : W1) + (size_t)e * DMODEL * DMODEL;
    __bf16*      dst = (which ? W2bt : W1bt) + (size_t)e * DMODEL * DMODEL;
    int r = tid >> 2;
    int cs = (tid & 3) * 16;
    int r0 = ty * 64, c0 = tx * 64;
    #pragma unroll
    for (int i = 0; i < 16; i += 4) {
      float4 v = *(const float4*)(src + (size_t)(r0 + r) * DMODEL + c0 + cs + i);
      tile[r][cs + i + 0] = v.x; tile[r][cs + i + 1] = v.y;
      tile[r][cs + i + 2] = v.z; tile[r][cs + i + 3] = v.w;
    }
    __syncthreads();
    bf16x8 o1, o2;
    #pragma unroll
    for (int i = 0; i < 8; i++) o1[i] = (__bf16)tile[cs + i][r];
    #pragma unroll
    for (int i = 0; i < 8; i++) o2[i] = (__bf16)tile[cs + 8 + i][r];
    {
      int n  = c0 + r;
      int g  = n >> 4, fr = n & 15;
      int k1 = r0 + cs;
      int c1 = k1 >> 5, fg1 = (k1 >> 3) & 3;
      int k2 = k1 + 8;
      int c2 = k2 >> 5, fg2 = (k2 >> 3) & 3;
      *(bf16x8*)(dst + ((size_t)(g * 32 + c1) * 512 + (fg1 * 16 + fr) * 8)) = o1;
      *(bf16x8*)(dst + ((size_t)(g * 32 + c2) * 512 + (fg2 * 16 + fr) * 8)) = o2;
    }
  } else {
    // ---------------- gate: 4 tokens per wave, fused X->bf16 ----------------
    float* gws = (float*)smem;               // 256 rows * 20 dwords = 20480 B
    float* rws = (float*)(smem + 20480);     // 256 dwords = 1024 B
    int g = bid / 9;                         // 0..1023
    int w = tid >> 6, lane = tid & 63;
    int n0t = g * 16 + w * 4;                // first of this wave's 4 tokens
    const float* xr0 = x + (size_t)(n0t + 0) * DMODEL;
    const float* xr1 = x + (size_t)(n0t + 1) * DMODEL;
    const float* xr2 = x + (size_t)(n0t + 2) * DMODEL;
    const float* xr3 = x + (size_t)(n0t + 3) * DMODEL;

    float acc0[17], acc1[17], acc2[17], acc3[17];
    #pragma unroll
    for (int j = 0; j < 17; j++) { acc0[j] = 0.f; acc1[j] = 0.f; acc2[j] = 0.f; acc3[j] = 0.f; }

    for (int c = 0; c < 4; c++) {
      int c0 = c * 256;
      __syncthreads();   // previous chunk fully consumed
      #pragma unroll
      for (int q = tid, it = 0; it < 4; q += 256, it++) {
        float4 v = *(const float4*)(gw + c0 * 16 + q * 4);
        *(float4*)(gws + (q >> 2) * 20 + (q & 3) * 4) = v;
      }
      rws[tid] = rw[c0 + tid];
      __syncthreads();

      #pragma unroll
      for (int dv = 0; dv < 4; dv++) {
        int dl = dv * 64 + lane;
        int d  = c0 + dl;
        float x0 = xr0[d], x1 = xr1[d], x2 = xr2[d], x3 = xr3[d];
        Xb[(size_t)(n0t + 0) * DMODEL + d] = (__bf16)x0;
        Xb[(size_t)(n0t + 1) * DMODEL + d] = (__bf16)x1;
        Xb[(size_t)(n0t + 2) * DMODEL + d] = (__bf16)x2;
        Xb[(size_t)(n0t + 3) * DMODEL + d] = (__bf16)x3;
        const float* gp = gws + dl * 20;
        float4 g0 = *(const float4*)(gp);
        float4 g1 = *(const float4*)(gp + 4);
        float4 g2 = *(const float4*)(gp + 8);
        float4 g3 = *(const float4*)(gp + 12);
        float rv = rws[dl];
        float gj[16] = {g0.x, g0.y, g0.z, g0.w, g1.x, g1.y, g1.z, g1.w,
                        g2.x, g2.y, g2.z, g2.w, g3.x, g3.y, g3.z, g3.w};
        #pragma unroll
        for (int j = 0; j < 16; j++) {
          acc0[j] += x0 * gj[j]; acc1[j] += x1 * gj[j];
          acc2[j] += x2 * gj[j]; acc3[j] += x3 * gj[j];
        }
        acc0[16] += x0 * rv; acc1[16] += x1 * rv;
        acc2[16] += x2 * rv; acc3[16] += x3 * rv;
      }
    }

    #pragma unroll
    for (int o = 1; o < 64; o <<= 1) {
      #pragma unroll
      for (int j = 0; j < 17; j++) {
        acc0[j] += __shfl_xor(acc0[j], o);
        acc1[j] += __shfl_xor(acc1[j], o);
        acc2[j] += __shfl_xor(acc2[j], o);
        acc3[j] += __shfl_xor(acc3[j], o);
      }
    }
    if (lane == 0) {
      float* accs[4] = {acc0, acc1, acc2, acc3};
      #pragma unroll
      for (int tk = 0; tk < 4; tk++) {
        float* acc = accs[tk];
        int n = n0t + tk;
        float rv = acc[16] + rb[0];
        bool g1f = rv > 0.f;
        float c[8];
        #pragma unroll
        for (int j = 0; j < 8; j++)
          c[j] = (g1f ? acc[j] + gb[j] : acc[8 + j] + gb[8 + j]);
        int i1 = 0; float v1 = c[0];
        #pragma unroll
        for (int j = 1; j < 8; j++) { if (c[j] > v1) { v1 = c[j]; i1 = j; } }
        int i2 = -1; float v2 = -3.4e38f;
        #pragma unroll
        for (int j = 0; j < 8; j++) { if (j != i1 && c[j] > v2) { v2 = c[j]; i2 = j; } }
        float e2 = expf(v2 - v1);
        float den = 1.f + e2;
        int base = g1f ? 0 : 8;
        idxo[2 * n] = base + i1; idxo[2 * n + 1] = base + i2;
        sco[2 * n] = 1.f / den;  sco[2 * n + 1] = e2 / den;
      }
    }
  }
}

// ------------- scan: t-ordered per-expert ranks, rowlists, offsets -------------
__global__ __launch_bounds__(1024) void scan_kernel(const int* __restrict__ idx,
                                                    float* __restrict__ sco,
                                                    int* __restrict__ rowlist,
                                                    int* __restrict__ cnt,
                                                    int* __restrict__ off) {
  __shared__ int hist[16 * 1024];   // 64 KB
  int tid = threadIdx.x;
  #pragma unroll
  for (int e = 0; e < 16; e++) hist[e * 1024 + tid] = 0;
  __syncthreads();
  int base = tid * 32;
  for (int i = 0; i < 32; i++) {
    int e = idx[base + i];
    hist[e * 1024 + tid]++;
  }
  __syncthreads();
  int w = tid >> 6, lane = tid & 63;
  {
    int e = w;  // 16 waves == 16 experts
    int running = 0;
    for (int cch = 0; cch < 16; cch++) {
      int v = hist[e * 1024 + cch * 64 + lane];
      int orig = v;
      #pragma unroll
      for (int o = 1; o < 64; o <<= 1) {
        int nv = __shfl_up(v, o);
        if (lane >= o) v += nv;
      }
      hist[e * 1024 + cch * 64 + lane] = running + v - orig;  // exclusive base
      running += __shfl(v, 63);
    }
    if (lane == 0) cnt[e] = running;   // raw count
  }
  __syncthreads();
  if (tid == 0) {
    int o = 0;
    for (int e = 0; e < 16; e++) {
      int c = cnt[e]; if (c > CAP) c = CAP;
      off[e] = o; cnt[e] = c; o += c;
    }
  }
  __syncthreads();
  for (int i = 0; i < 32; i++) {
    int t = base + i;
    int e = idx[t];
    int r = hist[e * 1024 + tid]++;
    if (r < CAP) rowlist[e * CAP + r] = t;
    else sco[t] = 0.f;   // dropped slot contributes zero
  }
}

// ------- grouped GEMM: 128x128x32, 4 waves, 32KB LDS dbuf -> 5 blocks/CU -------
// A LDS layout: two 64B rows per 128B line, granule-XOR swizzled:
//   element (row, chunk) -> line = row>>1, c = (row&1)*4+chunk,
//   slot byte = line*128 + (c ^ (line&7))*16.   (proven 0-conflict pattern)
// gl_lds dest stays linear; source (row,chunk) decoded from the inverse map.
// B: fragment-linear (lane*16B) — canonical conflict-free.
#define GBM 128
#define GBN 128
#define GBK 32
#define NKT (DMODEL / GBK)   // 32 K-steps

__global__ __launch_bounds__(256, 5) void moe_gemm(const __bf16* __restrict__ A,
                                                   const __bf16* __restrict__ Bf,
                                                   const float* __restrict__ bias,
                                                   __bf16* __restrict__ out,
                                                   const int* __restrict__ rowlist,
                                                   const int* __restrict__ cnt,
                                                   const int* __restrict__ off,
                                                   int mode) {
  __shared__ char lds[32768];   // A: 2x8KB @0, B: 2x8KB @16384
  int bx = blockIdx.x;
  // 512 x-blocks = 16 experts x 32 M-tiles; XCD-chunked bijective swizzle (512%8==0)
  int em = (bx & 7) * 64 + (bx >> 3);
  int e  = em >> 5;
  int m0 = (em & 31) * GBM;
  int ce = cnt[e];
  if (m0 >= ce) return;
  int n0 = blockIdx.y * GBN;
  int oe = off[e];
  int tid = threadIdx.x;

  // A staging sources: inverse of the LDS swizzle. slot lin -> (row, chunk):
  //   line = lin>>3, cswz = lin&7, c = cswz ^ (line&7), row = line*2 + (c>>2),
  //   chunk = c&3.
  const __bf16* aP[2];
  #pragma unroll
  for (int j = 0; j < 2; j++) {
    int lin = j * 256 + tid;
    int line = lin >> 3;
    int c = (lin & 7) ^ (line & 7);
    int srow = line * 2 + (c >> 2);
    int chunk = c & 3;
    int rr = m0 + srow; if (rr > ce - 1) rr = ce - 1;
    size_t arow;
    if (mode == 0) arow = (size_t)(rowlist[e * CAP + rr] >> 1);  // token id
    else           arow = (size_t)(oe + rr);                     // h row
    aP[j] = A + arow * DMODEL + chunk * 8;
  }
  // B staging sources: fragment-linear, group = lin>>6, lane-in-group = lin&63
  const __bf16* bP[2];
  int g0 = n0 >> 4;
  #pragma unroll
  for (int j = 0; j < 2; j++) {
    int lin = j * 256 + tid;
    int grp = lin >> 6;
    int ln  = lin & 63;
    bP[j] = Bf + (size_t)e * DMODEL * DMODEL
               + (size_t)((g0 + grp) * 32) * 512 + (size_t)ln * 8;
  }

  int w = tid >> 6, lane = tid & 63;
  int wr = (w >> 1) * 64;     // wave M-offset
  int wc = (w & 1) * 64;      // wave N-offset
  int fr = lane & 15, fg = lane >> 4;

  // A read: addr = buf + wr*64 + mi*1024 + (fr>>1)*128 + gkA
  int gkA = ((((fr & 1) * 4) | fg) ^ ((fr >> 1) & 7)) * 16;
  int aRd = wr * 64 + (fr >> 1) * 128 + gkA;
  int bRd = 16384 + (w & 1) * 4096 + lane * 16;     // + buf + ni*1024

  f32x4 acc[4][4];
  #pragma unroll
  for (int mi = 0; mi < 4; mi++)
    #pragma unroll
    for (int ni = 0; ni < 4; ni++)
      #pragma unroll
      for (int l = 0; l < 4; l++) acc[mi][ni][l] = 0.f;

  auto stA = [&](int s) {
    char* dst = lds + (s & 1) * 8192;
    gl_lds16(aP[0] + s * 32, dst + (size_t)tid * 16);
    gl_lds16(aP[1] + s * 32, dst + (size_t)(256 + tid) * 16);
  };
  auto stB = [&](int s) {
    char* dst = lds + 16384 + (s & 1) * 8192;
    gl_lds16(bP[0] + s * 512, dst + (size_t)tid * 16);
    gl_lds16(bP[1] + s * 512, dst + (size_t)(256 + tid) * 16);
  };

  // prologue: tiles 0 and 1 staged (8 instr); vmcnt(4) -> tile0 landed
  stA(0); stB(0); stA(1); stB(1);
  asm volatile("s_waitcnt vmcnt(4)" ::: "memory");
  BAR();

  for (int t = 0; t < NKT; ++t) {
    const char* Ab = lds + (t & 1) * 8192 + aRd;
    const char* Bb = lds + (t & 1) * 8192 + bRd;

    bf16x8 af[4], bq[4];
    #pragma unroll
    for (int mi = 0; mi < 4; mi++) af[mi] = *(const bf16x8*)(Ab + mi * 1024);
    #pragma unroll
    for (int ni = 0; ni < 4; ni++) bq[ni] = *(const bf16x8*)(Bb + ni * 1024);
    asm volatile("s_waitcnt lgkmcnt(0)" ::: "memory");
    __builtin_amdgcn_sched_barrier(0);
    __builtin_amdgcn_s_setprio(1);
    #pragma unroll
    for (int mi = 0; mi < 4; mi++) {
      acc[mi][0] = __builtin_amdgcn_mfma_f32_16x16x32_bf16(af[mi], bq[0], acc[mi][0], 0, 0, 0);
      acc[mi][1] = __builtin_amdgcn_mfma_f32_16x16x32_bf16(af[mi], bq[1], acc[mi][1], 0, 0, 0);
    }
    __builtin_amdgcn_s_setprio(0);
    BAR();   // all waves' reads of buf (t&1) complete

    if (t <= NKT - 3) { stA(t + 2); stB(t + 2); }
    __builtin_amdgcn_s_setprio(1);
    #pragma unroll
    for (int mi = 0; mi < 4; mi++) {
      acc[mi][2] = __builtin_amdgcn_mfma_f32_16x16x32_bf16(af[mi], bq[2], acc[mi][2], 0, 0, 0);
      acc[mi][3] = __builtin_amdgcn_mfma_f32_16x16x32_bf16(af[mi], bq[3], acc[mi][3], 0, 0, 0);
    }
    __builtin_amdgcn_s_setprio(0);
    if (t <= NKT - 3)      asm volatile("s_waitcnt vmcnt(4)" ::: "memory");
    else if (t == NKT - 2) asm volatile("s_waitcnt vmcnt(0)" ::: "memory");
    BAR();
  }

  float bcol[4];
  #pragma unroll
  for (int ni = 0; ni < 4; ni++)
    bcol[ni] = bias[(size_t)e * DMODEL + n0 + wc + ni * 16 + fr];
  #pragma unroll
  for (int mi = 0; mi < 4; mi++) {
    #pragma unroll
    for (int r = 0; r < 4; r++) {
      int grow = m0 + wr + mi * 16 + fg * 4 + r;
      if (grow >= ce) continue;
      size_t orow = (mode == 0) ? (size_t)(oe + grow)
                                : (size_t)rowlist[e * CAP + grow];
      __bf16* op = out + orow * DMODEL + n0 + wc + fr;
      #pragma unroll
      for (int ni = 0; ni < 4; ni++) {
        float v = acc[mi][ni][r] + bcol[ni];
        if (mode == 0) v = fmaxf(v, 0.f);
        op[ni * 16] = (__bf16)v;
      }
    }
  }
}

// ---------------- combine: out[n] = s0*y[2n] + s1*y[2n+1] ----------------
__global__ __launch_bounds__(256) void combine_kernel(const __bf16* __restrict__ y,
                                                      const float* __restrict__ sco,
                                                      float* __restrict__ out) {
  int n = blockIdx.x;
  int d = threadIdx.x * 4;
  float s0 = sco[2 * n], s1 = sco[2 * n + 1];
  ushort4 a = *(const ushort4*)((const unsigned short*)(y + (size_t)(2 * n) * DMODEL + d));
  ushort4 b = *(const ushort4*)((const unsigned short*)(y + (size_t)(2 * n + 1) * DMODEL + d));
  float4 o;
  o.x = s0 * bfbits2f(a.x) + s1 * bfbits2f(b.x);
  o.y = s0 * bfbits2f(a.y) + s1 * bfbits2f(b.y);
  o.z = s0 * bfbits2f(a.z) + s1 * bfbits2f(b.z);
  o.w = s0 * bfbits2f(a.w) + s1 * bfbits2f(b.w);
  *(float4*)(out + (size_t)n * DMODEL + d) = o;
}

extern "C" void kernel_launch(void* const* d_in, const int* in_sizes, int n_in,
                              void* d_out, int out_size, void* d_ws, size_t ws_size,
                              hipStream_t stream) {
  const float* moe = (const float*)d_in[0];
  const float* gw  = (const float*)d_in[1];
  const float* gb  = (const float*)d_in[2];
  const float* rw  = (const float*)d_in[3];
  const float* rb  = (const float*)d_in[4];
  const float* W1  = (const float*)d_in[5];
  const float* b1  = (const float*)d_in[6];
  const float* W2  = (const float*)d_in[7];
  const float* b2  = (const float*)d_in[8];
  float* out = (float*)d_out;

  char* p = (char*)d_ws;
  __bf16* Xb   = (__bf16*)p; p += (size_t)N_TOK * DMODEL * 2;
  __bf16* W1bt = (__bf16*)p; p += (size_t)EXP * DMODEL * DMODEL * 2;
  __bf16* W2bt = (__bf16*)p; p += (size_t)EXP * DMODEL * DMODEL * 2;
  __bf16* hbuf = (__bf16*)p; p += (size_t)TT * DMODEL * 2;
  __bf16* ybuf = (__bf16*)p; p += (size_t)TT * DMODEL * 2;
  int*   idxb   = (int*)p;   p += (size_t)TT * 4;
  float* scoreb = (float*)p; p += (size_t)TT * 4;
  int*   rowlist = (int*)p;  p += (size_t)EXP * CAP * 4;
  int*   cntb    = (int*)p;  p += 64;
  int*   offb    = (int*)p;  p += 64;

  prep_kernel<<<dim3(9216), dim3(256), 0, stream>>>(W1, W2, W1bt, W2bt,
                                                    moe, gw, gb, rw, rb,
                                                    idxb, scoreb, Xb);
  scan_kernel<<<dim3(1), dim3(1024), 0, stream>>>(idxb, scoreb, rowlist, cntb, offb);
  moe_gemm<<<dim3(512, 8), dim3(256), 0, stream>>>(Xb, W1bt, b1, hbuf, rowlist, cntb, offb, 0);
  moe_gemm<<<dim3(512, 8), dim3(256), 0, stream>>>(hbuf, W2bt, b2, ybuf, rowlist, cntb, offb, 1);
  combine_kernel<<<dim3(16384), dim3(256), 0, stream>>>(ybuf, scoreb, out);
}

// Round 14
// 344.810 us; speedup vs baseline: 3.1104x; 3.1104x over previous
//
#include <hip/hip_runtime.h>
#include <hip/hip_bf16.h>
#include <stdint.h>

#define N_TOK 16384
#define DMODEL 1024
#define EXP 16
#define CAP 4096
#define TT 32768          // N_TOK * K (K=2)

typedef __bf16 bf16x8 __attribute__((ext_vector_type(8)));
typedef __bf16 bf16x4 __attribute__((ext_vector_type(4)));
typedef float  f32x4  __attribute__((ext_vector_type(4)));

__device__ __forceinline__ void gl_lds16(const void* g, void* s) {
  __builtin_amdgcn_global_load_lds(
      (__attribute__((address_space(1))) void*)(void*)g,
      (__attribute__((address_space(3))) void*)s, 16, 0, 0);
}

__device__ __forceinline__ float bfbits2f(unsigned short u) {
  return __uint_as_float(((unsigned)u) << 16);
}

#define FENCE asm volatile("" ::: "memory")
#define BAR() do { FENCE; __builtin_amdgcn_s_barrier(); FENCE; } while (0)

// ------- merged prep, interleaved: bid%9==8 -> gate (1024), else convw (8192) -------
// convw writes W in MFMA-fragment-linear layout:
//   W^T[n][k] -> Wf[e*1M + ((n>>4)*32 + (k>>5))*512 + (((k>>3)&3)*16 + (n&15))*8 + (k&7)]
__global__ __launch_bounds__(256) void prep_kernel(const float* __restrict__ W1,
                                                   const float* __restrict__ W2,
                                                   __bf16* __restrict__ W1bt,
                                                   __bf16* __restrict__ W2bt,
                                                   const float* __restrict__ x,
                                                   const float* __restrict__ gw,
                                                   const float* __restrict__ gb,
                                                   const float* __restrict__ rw,
                                                   const float* __restrict__ rb,
                                                   int* __restrict__ idxo,
                                                   float* __restrict__ sco,
                                                   __bf16* __restrict__ Xb) {
  __shared__ char smem[21504];
  int bid = blockIdx.x;
  int tid = threadIdx.x;
  if (bid % 9 != 8) {
    // ---------------- convw (fragment-linear output) ----------------
    int cb = bid - (bid + 1) / 9;          // 0..8191 bijective
    float (*tile)[65] = (float(*)[65])smem;
    int tx = cb & 15;
    int ty = (cb >> 4) & 15;
    int e  = (cb >> 8) & 15;
    int which = (cb >> 12) & 1;
    const float* src = (which ? W2 : W1) + (size_t)e * DMODEL * DMODEL;
    __bf16*      dst = (which ? W2bt : W1bt) + (size_t)e * DMODEL * DMODEL;
    int r = tid >> 2;
    int cs = (tid & 3) * 16;
    int r0 = ty * 64, c0 = tx * 64;
    #pragma unroll
    for (int i = 0; i < 16; i += 4) {
      float4 v = *(const float4*)(src + (size_t)(r0 + r) * DMODEL + c0 + cs + i);
      tile[r][cs + i + 0] = v.x; tile[r][cs + i + 1] = v.y;
      tile[r][cs + i + 2] = v.z; tile[r][cs + i + 3] = v.w;
    }
    __syncthreads();
    bf16x8 o1, o2;
    #pragma unroll
    for (int i = 0; i < 8; i++) o1[i] = (__bf16)tile[cs + i][r];
    #pragma unroll
    for (int i = 0; i < 8; i++) o2[i] = (__bf16)tile[cs + 8 + i][r];
    {
      int n  = c0 + r;
      int g  = n >> 4, fr = n & 15;
      int k1 = r0 + cs;
      int c1 = k1 >> 5, fg1 = (k1 >> 3) & 3;
      int k2 = k1 + 8;
      int c2 = k2 >> 5, fg2 = (k2 >> 3) & 3;
      *(bf16x8*)(dst + ((size_t)(g * 32 + c1) * 512 + (fg1 * 16 + fr) * 8)) = o1;
      *(bf16x8*)(dst + ((size_t)(g * 32 + c2) * 512 + (fg2 * 16 + fr) * 8)) = o2;
    }
  } else {
    // ---------------- gate: 4 tokens per wave, fused X->bf16 ----------------
    float* gws = (float*)smem;               // 256 rows * 20 dwords = 20480 B
    float* rws = (float*)(smem + 20480);     // 256 dwords = 1024 B
    int g = bid / 9;                         // 0..1023
    int w = tid >> 6, lane = tid & 63;
    int n0t = g * 16 + w * 4;                // first of this wave's 4 tokens
    const float* xr0 = x + (size_t)(n0t + 0) * DMODEL;
    const float* xr1 = x + (size_t)(n0t + 1) * DMODEL;
    const float* xr2 = x + (size_t)(n0t + 2) * DMODEL;
    const float* xr3 = x + (size_t)(n0t + 3) * DMODEL;

    float acc0[17], acc1[17], acc2[17], acc3[17];
    #pragma unroll
    for (int j = 0; j < 17; j++) { acc0[j] = 0.f; acc1[j] = 0.f; acc2[j] = 0.f; acc3[j] = 0.f; }

    for (int c = 0; c < 4; c++) {
      int c0 = c * 256;
      __syncthreads();   // previous chunk fully consumed
      #pragma unroll
      for (int q = tid, it = 0; it < 4; q += 256, it++) {
        float4 v = *(const float4*)(gw + c0 * 16 + q * 4);
        *(float4*)(gws + (q >> 2) * 20 + (q & 3) * 4) = v;
      }
      rws[tid] = rw[c0 + tid];
      __syncthreads();

      #pragma unroll
      for (int dv = 0; dv < 4; dv++) {
        int dl = dv * 64 + lane;
        int d  = c0 + dl;
        float x0 = xr0[d], x1 = xr1[d], x2 = xr2[d], x3 = xr3[d];
        Xb[(size_t)(n0t + 0) * DMODEL + d] = (__bf16)x0;
        Xb[(size_t)(n0t + 1) * DMODEL + d] = (__bf16)x1;
        Xb[(size_t)(n0t + 2) * DMODEL + d] = (__bf16)x2;
        Xb[(size_t)(n0t + 3) * DMODEL + d] = (__bf16)x3;
        const float* gp = gws + dl * 20;
        float4 g0 = *(const float4*)(gp);
        float4 g1 = *(const float4*)(gp + 4);
        float4 g2 = *(const float4*)(gp + 8);
        float4 g3 = *(const float4*)(gp + 12);
        float rv = rws[dl];
        float gj[16] = {g0.x, g0.y, g0.z, g0.w, g1.x, g1.y, g1.z, g1.w,
                        g2.x, g2.y, g2.z, g2.w, g3.x, g3.y, g3.z, g3.w};
        #pragma unroll
        for (int j = 0; j < 16; j++) {
          acc0[j] += x0 * gj[j]; acc1[j] += x1 * gj[j];
          acc2[j] += x2 * gj[j]; acc3[j] += x3 * gj[j];
        }
        acc0[16] += x0 * rv; acc1[16] += x1 * rv;
        acc2[16] += x2 * rv; acc3[16] += x3 * rv;
      }
    }

    #pragma unroll
    for (int o = 1; o < 64; o <<= 1) {
      #pragma unroll
      for (int j = 0; j < 17; j++) {
        acc0[j] += __shfl_xor(acc0[j], o);
        acc1[j] += __shfl_xor(acc1[j], o);
        acc2[j] += __shfl_xor(acc2[j], o);
        acc3[j] += __shfl_xor(acc3[j], o);
      }
    }
    if (lane == 0) {
      float* accs[4] = {acc0, acc1, acc2, acc3};
      #pragma unroll
      for (int tk = 0; tk < 4; tk++) {
        float* acc = accs[tk];
        int n = n0t + tk;
        float rv = acc[16] + rb[0];
        bool g1f = rv > 0.f;
        float c[8];
        #pragma unroll
        for (int j = 0; j < 8; j++)
          c[j] = (g1f ? acc[j] + gb[j] : acc[8 + j] + gb[8 + j]);
        int i1 = 0; float v1 = c[0];
        #pragma unroll
        for (int j = 1; j < 8; j++) { if (c[j] > v1) { v1 = c[j]; i1 = j; } }
        int i2 = -1; float v2 = -3.4e38f;
        #pragma unroll
        for (int j = 0; j < 8; j++) { if (j != i1 && c[j] > v2) { v2 = c[j]; i2 = j; } }
        float e2 = expf(v2 - v1);
        float den = 1.f + e2;
        int base = g1f ? 0 : 8;
        idxo[2 * n] = base + i1; idxo[2 * n + 1] = base + i2;
        sco[2 * n] = 1.f / den;  sco[2 * n + 1] = e2 / den;
      }
    }
  }
}

// ------------- scan: t-ordered per-expert ranks, rowlists, offsets -------------
__global__ __launch_bounds__(1024) void scan_kernel(const int* __restrict__ idx,
                                                    float* __restrict__ sco,
                                                    int* __restrict__ rowlist,
                                                    int* __restrict__ cnt,
                                                    int* __restrict__ off) {
  __shared__ int hist[16 * 1024];   // 64 KB
  int tid = threadIdx.x;
  #pragma unroll
  for (int e = 0; e < 16; e++) hist[e * 1024 + tid] = 0;
  __syncthreads();
  int base = tid * 32;
  for (int i = 0; i < 32; i++) {
    int e = idx[base + i];
    hist[e * 1024 + tid]++;
  }
  __syncthreads();
  int w = tid >> 6, lane = tid & 63;
  {
    int e = w;  // 16 waves == 16 experts
    int running = 0;
    for (int cch = 0; cch < 16; cch++) {
      int v = hist[e * 1024 + cch * 64 + lane];
      int orig = v;
      #pragma unroll
      for (int o = 1; o < 64; o <<= 1) {
        int nv = __shfl_up(v, o);
        if (lane >= o) v += nv;
      }
      hist[e * 1024 + cch * 64 + lane] = running + v - orig;  // exclusive base
      running += __shfl(v, 63);
    }
    if (lane == 0) cnt[e] = running;   // raw count
  }
  __syncthreads();
  if (tid == 0) {
    int o = 0;
    for (int e = 0; e < 16; e++) {
      int c = cnt[e]; if (c > CAP) c = CAP;
      off[e] = o; cnt[e] = c; o += c;
    }
  }
  __syncthreads();
  for (int i = 0; i < 32; i++) {
    int t = base + i;
    int e = idx[t];
    int r = hist[e * 1024 + tid]++;
    if (r < CAP) rowlist[e * CAP + r] = t;
    else sco[t] = 0.f;   // dropped slot contributes zero
  }
}

// ------- grouped GEMM: 128x128x32, 4 waves, 32KB LDS dbuf -> 4 blocks/CU -------
// A LDS layout: two 64B rows per 128B line, granule-XOR swizzled:
//   element (row, chunk) -> line = row>>1, c = (row&1)*4+chunk,
//   slot byte = line*128 + (c ^ (line&7))*16.   (conflict-free pattern)
// gl_lds dest stays linear; source (row,chunk) decoded from the inverse map.
// B: fragment-linear (lane*16B) — canonical conflict-free.
#define GBM 128
#define GBN 128
#define GBK 32
#define NKT (DMODEL / GBK)   // 32 K-steps

__global__ __launch_bounds__(256, 4) void moe_gemm(const __bf16* __restrict__ A,
                                                   const __bf16* __restrict__ Bf,
                                                   const float* __restrict__ bias,
                                                   __bf16* __restrict__ out,
                                                   const int* __restrict__ rowlist,
                                                   const int* __restrict__ cnt,
                                                   const int* __restrict__ off,
                                                   int mode) {
  __shared__ char lds[32768];   // A: 2x8KB @0, B: 2x8KB @16384
  int bx = blockIdx.x;
  // 512 x-blocks = 16 experts x 32 M-tiles; XCD-chunked bijective swizzle (512%8==0)
  int em = (bx & 7) * 64 + (bx >> 3);
  int e  = em >> 5;
  int m0 = (em & 31) * GBM;
  int ce = cnt[e];
  if (m0 >= ce) return;
  int n0 = blockIdx.y * GBN;
  int oe = off[e];
  int tid = threadIdx.x;

  // A staging sources: inverse of the LDS swizzle. slot lin -> (row, chunk):
  //   line = lin>>3, cswz = lin&7, c = cswz ^ (line&7), row = line*2 + (c>>2),
  //   chunk = c&3.
  const __bf16* aP[2];
  #pragma unroll
  for (int j = 0; j < 2; j++) {
    int lin = j * 256 + tid;
    int line = lin >> 3;
    int c = (lin & 7) ^ (line & 7);
    int srow = line * 2 + (c >> 2);
    int chunk = c & 3;
    int rr = m0 + srow; if (rr > ce - 1) rr = ce - 1;
    size_t arow;
    if (mode == 0) arow = (size_t)(rowlist[e * CAP + rr] >> 1);  // token id
    else           arow = (size_t)(oe + rr);                     // h row
    aP[j] = A + arow * DMODEL + chunk * 8;
  }
  // B staging sources: fragment-linear, group = lin>>6, lane-in-group = lin&63
  const __bf16* bP[2];
  int g0 = n0 >> 4;
  #pragma unroll
  for (int j = 0; j < 2; j++) {
    int lin = j * 256 + tid;
    int grp = lin >> 6;
    int ln  = lin & 63;
    bP[j] = Bf + (size_t)e * DMODEL * DMODEL
               + (size_t)((g0 + grp) * 32) * 512 + (size_t)ln * 8;
  }

  int w = tid >> 6, lane = tid & 63;
  int wr = (w >> 1) * 64;     // wave M-offset
  int wc = (w & 1) * 64;      // wave N-offset
  int fr = lane & 15, fg = lane >> 4;

  // A read: addr = buf + wr*64 + mi*1024 + (fr>>1)*128 + gkA
  int gkA = ((((fr & 1) * 4) | fg) ^ ((fr >> 1) & 7)) * 16;
  int aRd = wr * 64 + (fr >> 1) * 128 + gkA;
  int bRd = 16384 + (w & 1) * 4096 + lane * 16;     // + buf + ni*1024

  f32x4 acc[4][4];
  #pragma unroll
  for (int mi = 0; mi < 4; mi++)
    #pragma unroll
    for (int ni = 0; ni < 4; ni++)
      #pragma unroll
      for (int l = 0; l < 4; l++) acc[mi][ni][l] = 0.f;

  auto stA = [&](int s) {
    char* dst = lds + (s & 1) * 8192;
    gl_lds16(aP[0] + s * 32, dst + (size_t)tid * 16);
    gl_lds16(aP[1] + s * 32, dst + (size_t)(256 + tid) * 16);
  };
  auto stB = [&](int s) {
    char* dst = lds + 16384 + (s & 1) * 8192;
    gl_lds16(bP[0] + s * 512, dst + (size_t)tid * 16);
    gl_lds16(bP[1] + s * 512, dst + (size_t)(256 + tid) * 16);
  };

  // prologue: tiles 0 and 1 staged (8 instr); vmcnt(4) -> tile0 landed
  stA(0); stB(0); stA(1); stB(1);
  asm volatile("s_waitcnt vmcnt(4)" ::: "memory");
  BAR();

  for (int t = 0; t < NKT; ++t) {
    const char* Ab = lds + (t & 1) * 8192 + aRd;
    const char* Bb = lds + (t & 1) * 8192 + bRd;

    bf16x8 af[4], bq[4];
    #pragma unroll
    for (int mi = 0; mi < 4; mi++) af[mi] = *(const bf16x8*)(Ab + mi * 1024);
    #pragma unroll
    for (int ni = 0; ni < 4; ni++) bq[ni] = *(const bf16x8*)(Bb + ni * 1024);
    asm volatile("s_waitcnt lgkmcnt(0)" ::: "memory");
    __builtin_amdgcn_sched_barrier(0);
    __builtin_amdgcn_s_setprio(1);
    #pragma unroll
    for (int mi = 0; mi < 4; mi++) {
      acc[mi][0] = __builtin_amdgcn_mfma_f32_16x16x32_bf16(af[mi], bq[0], acc[mi][0], 0, 0, 0);
      acc[mi][1] = __builtin_amdgcn_mfma_f32_16x16x32_bf16(af[mi], bq[1], acc[mi][1], 0, 0, 0);
    }
    __builtin_amdgcn_s_setprio(0);
    BAR();   // all waves' reads of buf (t&1) complete

    if (t <= NKT - 3) { stA(t + 2); stB(t + 2); }
    __builtin_amdgcn_s_setprio(1);
    #pragma unroll
    for (int mi = 0; mi < 4; mi++) {
      acc[mi][2] = __builtin_amdgcn_mfma_f32_16x16x32_bf16(af[mi], bq[2], acc[mi][2], 0, 0, 0);
      acc[mi][3] = __builtin_amdgcn_mfma_f32_16x16x32_bf16(af[mi], bq[3], acc[mi][3], 0, 0, 0);
    }
    __builtin_amdgcn_s_setprio(0);
    if (t <= NKT - 3)      asm volatile("s_waitcnt vmcnt(4)" ::: "memory");
    else if (t == NKT - 2) asm volatile("s_waitcnt vmcnt(0)" ::: "memory");
    BAR();
  }

  float bcol[4];
  #pragma unroll
  for (int ni = 0; ni < 4; ni++)
    bcol[ni] = bias[(size_t)e * DMODEL + n0 + wc + ni * 16 + fr];
  #pragma unroll
  for (int mi = 0; mi < 4; mi++) {
    #pragma unroll
    for (int r = 0; r < 4; r++) {
      int grow = m0 + wr + mi * 16 + fg * 4 + r;
      if (grow >= ce) continue;
      size_t orow = (mode == 0) ? (size_t)(oe + grow)
                                : (size_t)rowlist[e * CAP + grow];
      __bf16* op = out + orow * DMODEL + n0 + wc + fr;
      #pragma unroll
      for (int ni = 0; ni < 4; ni++) {
        float v = acc[mi][ni][r] + bcol[ni];
        if (mode == 0) v = fmaxf(v, 0.f);
        op[ni * 16] = (__bf16)v;
      }
    }
  }
}

// ---------------- combine: out[n] = s0*y[2n] + s1*y[2n+1] ----------------
__global__ __launch_bounds__(256) void combine_kernel(const __bf16* __restrict__ y,
                                                      const float* __restrict__ sco,
                                                      float* __restrict__ out) {
  int n = blockIdx.x;
  int d = threadIdx.x * 4;
  float s0 = sco[2 * n], s1 = sco[2 * n + 1];
  ushort4 a = *(const ushort4*)((const unsigned short*)(y + (size_t)(2 * n) * DMODEL + d));
  ushort4 b = *(const ushort4*)((const unsigned short*)(y + (size_t)(2 * n + 1) * DMODEL + d));
  float4 o;
  o.x = s0 * bfbits2f(a.x) + s1 * bfbits2f(b.x);
  o.y = s0 * bfbits2f(a.y) + s1 * bfbits2f(b.y);
  o.z = s0 * bfbits2f(a.z) + s1 * bfbits2f(b.z);
  o.w = s0 * bfbits2f(a.w) + s1 * bfbits2f(b.w);
  *(float4*)(out + (size_t)n * DMODEL + d) = o;
}

extern "C" void kernel_launch(void* const* d_in, const int* in_sizes, int n_in,
                              void* d_out, int out_size, void* d_ws, size_t ws_size,
                              hipStream_t stream) {
  const float* moe = (const float*)d_in[0];
  const float* gw  = (const float*)d_in[1];
  const float* gb  = (const float*)d_in[2];
  const float* rw  = (const float*)d_in[3];
  const float* rb  = (const float*)d_in[4];
  const float* W1  = (const float*)d_in[5];
  const float* b1  = (const float*)d_in[6];
  const float* W2  = (const float*)d_in[7];
  const float* b2  = (const float*)d_in[8];
  float* out = (float*)d_out;

  char* p = (char*)d_ws;
  __bf16* Xb   = (__bf16*)p; p += (size_t)N_TOK * DMODEL * 2;
  __bf16* W1bt = (__bf16*)p; p += (size_t)EXP * DMODEL * DMODEL * 2;
  __bf16* W2bt = (__bf16*)p; p += (size_t)EXP * DMODEL * DMODEL * 2;
  __bf16* hbuf = (__bf16*)p; p += (size_t)TT * DMODEL * 2;
  __bf16* ybuf = (__bf16*)p; p += (size_t)TT * DMODEL * 2;
  int*   idxb   = (int*)p;   p += (size_t)TT * 4;
  float* scoreb = (float*)p; p += (size_t)TT * 4;
  int*   rowlist = (int*)p;  p += (size_t)EXP * CAP * 4;
  int*   cntb    = (int*)p;  p += 64;
  int*   offb    = (int*)p;  p += 64;

  prep_kernel<<<dim3(9216), dim3(256), 0, stream>>>(W1, W2, W1bt, W2bt,
                                                    moe, gw, gb, rw, rb,
                                                    idxb, scoreb, Xb);
  scan_kernel<<<dim3(1), dim3(1024), 0, stream>>>(idxb, scoreb, rowlist, cntb, offb);
  moe_gemm<<<dim3(512, 8), dim3(256), 0, stream>>>(Xb, W1bt, b1, hbuf, rowlist, cntb, offb, 0);
  moe_gemm<<<dim3(512, 8), dim3(256), 0, stream>>>(hbuf, W2bt, b2, ybuf, rowlist, cntb, offb, 1);
  combine_kernel<<<dim3(16384), dim3(256), 0, stream>>>(ybuf, scoreb, out);
}